// Round 1
// 1009.884 us; speedup vs baseline: 1.5028x; 1.5028x over previous
//
#include <hip/hip_runtime.h>
#include <math.h>

#define B 2048
#define D_IN 512
#define D_MODEL 1024
#define ED 2048
#define NSTATE 16
#define KCONV 4
#define DTDIM 64
#define FLAT_H (ED * NSTATE)                    /* 32768 */
#define ROW_STATE (FLAT_H + ED * (KCONV - 1))   /* 38912 */

typedef __attribute__((ext_vector_type(8))) short short8;   // 8 x bf16 (4 VGPRs)
typedef __attribute__((ext_vector_type(4))) short short4v;  // 4 x bf16 (8B)
typedef __attribute__((ext_vector_type(4))) float f32x4;

__device__ __forceinline__ float sigmoidf_(float x) { return 1.f / (1.f + expf(-x)); }

// round-to-nearest-even fp32 -> bf16 bits
__device__ __forceinline__ unsigned short f2bf(float f) {
  unsigned u = __float_as_uint(f);
  u += 0x7FFFu + ((u >> 16) & 1u);
  return (unsigned short)(u >> 16);
}
__device__ __forceinline__ float bf2f(unsigned short h) {
  return __uint_as_float((unsigned)h << 16);
}

// ---------------------------------------------------------------------------
// Split-bf16 MFMA NT-GEMM: C[m,n] = sum_k A[m,k] * W[n,k]  (+ epilogue)
// fp32 precision via a = a_hi + a_lo (both bf16): hi*hi + hi*lo + lo*hi,
// dropped lo*lo term is ~2^-18 relative.
// 128x128 tile, BK=32, 256 threads = 4 waves (2x2), each wave 64x64 via
// 4x4 frags of v_mfma_f32_16x16x32_bf16.
// REQUIRES: M%128==0, N%128==0, K%32==0, all row strides %4==0 (float4 loads).
// MODE 0: plain store   MODE 1: softplus(v + extra[n])   MODE 2: v + extra[m*ldc+n]
// ---------------------------------------------------------------------------
template <int MODE>
__global__ __launch_bounds__(256) void gemm_nt_mfma(
    const float* __restrict__ A, const float* __restrict__ W,
    float* __restrict__ C, int M, int N, int K, int lda, int ldw, int ldc,
    const float* __restrict__ extra) {
  // [kgroup][row][8 k-elems] bf16: a 16-lane frag-read covers 256 contiguous
  // bytes -> conflict-free ds_read_b128.
  __shared__ short Ahi[4][128][8];
  __shared__ short Alo[4][128][8];
  __shared__ short Whi[4][128][8];
  __shared__ short Wlo[4][128][8];

  const int tid = threadIdx.x;
  const int lane = tid & 63;
  const int wave = tid >> 6;      // 0..3
  const int wr = wave >> 1;       // wave row (m)  0..1
  const int wc = wave & 1;        // wave col (n)  0..1
  const int m0 = blockIdx.y * 128;
  const int n0 = blockIdx.x * 128;
  const int kg = lane >> 4;       // k-group 0..3
  const int lr = lane & 15;       // row/col within frag

  f32x4 acc[4][4] = {};

  for (int k0 = 0; k0 < K; k0 += 32) {
    // ---- stage: load fp32, split into hi/lo bf16, write LDS ----
#pragma unroll
    for (int it = 0; it < 4; ++it) {
      const int flat = tid + it * 256;   // 0..1023
      const int row = flat >> 3;         // 0..127
      const int kq = flat & 7;           // k-quad 0..7
      const int tkg = kq >> 1;
      const int j0 = (kq & 1) * 4;
      const float4 av = *(const float4*)(A + (size_t)(m0 + row) * lda + (k0 + kq * 4));
      const float4 wv = *(const float4*)(W + (size_t)(n0 + row) * ldw + (k0 + kq * 4));
      const float af[4] = {av.x, av.y, av.z, av.w};
      const float wf[4] = {wv.x, wv.y, wv.z, wv.w};
      short4v ah, al, wh, wl;
#pragma unroll
      for (int e = 0; e < 4; ++e) {
        const unsigned short h = f2bf(af[e]);
        ah[e] = (short)h;
        al[e] = (short)f2bf(af[e] - bf2f(h));
        const unsigned short hw = f2bf(wf[e]);
        wh[e] = (short)hw;
        wl[e] = (short)f2bf(wf[e] - bf2f(hw));
      }
      *(short4v*)&Ahi[tkg][row][j0] = ah;
      *(short4v*)&Alo[tkg][row][j0] = al;
      *(short4v*)&Whi[tkg][row][j0] = wh;
      *(short4v*)&Wlo[tkg][row][j0] = wl;
    }
    __syncthreads();

    // ---- fragments + MFMA ----
    short8 a_h[4], a_l[4], b_h[4], b_l[4];
#pragma unroll
    for (int i = 0; i < 4; ++i) {
      a_h[i] = *(const short8*)&Ahi[kg][wr * 64 + i * 16 + lr][0];
      a_l[i] = *(const short8*)&Alo[kg][wr * 64 + i * 16 + lr][0];
      b_h[i] = *(const short8*)&Whi[kg][wc * 64 + i * 16 + lr][0];
      b_l[i] = *(const short8*)&Wlo[kg][wc * 64 + i * 16 + lr][0];
    }
#pragma unroll
    for (int i = 0; i < 4; ++i)
#pragma unroll
      for (int j = 0; j < 4; ++j) {
        acc[i][j] = __builtin_amdgcn_mfma_f32_16x16x32_bf16(a_h[i], b_h[j], acc[i][j], 0, 0, 0);
        acc[i][j] = __builtin_amdgcn_mfma_f32_16x16x32_bf16(a_l[i], b_h[j], acc[i][j], 0, 0, 0);
        acc[i][j] = __builtin_amdgcn_mfma_f32_16x16x32_bf16(a_h[i], b_l[j], acc[i][j], 0, 0, 0);
      }
    __syncthreads();
  }

  // ---- epilogue: C/D layout col = lane&15, row = (lane>>4)*4 + reg ----
#pragma unroll
  for (int i = 0; i < 4; ++i) {
    const int gm = m0 + wr * 64 + i * 16 + kg * 4;
#pragma unroll
    for (int j = 0; j < 4; ++j) {
      const int gn = n0 + wc * 64 + j * 16 + lr;
#pragma unroll
      for (int r = 0; r < 4; ++r) {
        float v = acc[i][j][r];
        if (MODE == 1) {
          v += extra[gn];
          v = (v > 20.f) ? v : log1pf(expf(v));
        } else if (MODE == 2) {
          v += extra[(size_t)(gm + r) * ldc + gn];
        }
        C[(size_t)(gm + r) * ldc + gn] = v;
      }
    }
  }
}

// ---------------------------------------------------------------------------
// Scalar fp32 NT-GEMM with split-K (grid.z), atomicAdd accumulate.
// Used only for dbc (N=96, not a multiple of 128). C must be pre-zeroed.
// ---------------------------------------------------------------------------
__global__ __launch_bounds__(256) void gemm_nt_splitk(
    const float* __restrict__ A, const float* __restrict__ W,
    float* __restrict__ C, int M, int N, int K, int lda, int ldw, int ldc) {
  __shared__ float As[16][68];
  __shared__ float Ws[16][68];
  const int tid = threadIdx.x;
  const int tx = tid & 15;
  const int ty = tid >> 4;
  const int m0 = blockIdx.y * 64;
  const int n0 = blockIdx.x * 64;
  const int kchunk = K / gridDim.z;
  const int kbeg = blockIdx.z * kchunk;

  float acc[4][4] = {};
  const int lr = tid >> 4;
  const int lc = tid & 15;

  for (int k0 = kbeg; k0 < kbeg + kchunk; k0 += 16) {
#pragma unroll
    for (int i = 0; i < 4; i++) {
      const int r = lr + i * 16;
      const int gk = k0 + lc;
      As[lc][r] = A[(size_t)(m0 + r) * lda + gk];
      const int gn = n0 + r;
      Ws[lc][r] = (gn < N) ? W[(size_t)gn * ldw + gk] : 0.f;
    }
    __syncthreads();
#pragma unroll
    for (int k = 0; k < 16; k++) {
      float a[4], w[4];
#pragma unroll
      for (int i = 0; i < 4; i++) a[i] = As[k][ty * 4 + i];
#pragma unroll
      for (int j = 0; j < 4; j++) w[j] = Ws[k][tx * 4 + j];
#pragma unroll
      for (int i = 0; i < 4; i++)
#pragma unroll
        for (int j = 0; j < 4; j++) acc[i][j] += a[i] * w[j];
    }
    __syncthreads();
  }

#pragma unroll
  for (int i = 0; i < 4; i++) {
    const int gm = m0 + ty * 4 + i;
#pragma unroll
    for (int j = 0; j < 4; j++) {
      const int gn = n0 + tx * 4 + j;
      if (gn >= N) continue;
      atomicAdd(&C[(size_t)gm * ldc + gn], acc[i][j]);
    }
  }
}

// ---------------------------------------------------------------------------
// RMSNorm: one block per row of x (D_MODEL=1024)
// ---------------------------------------------------------------------------
__global__ __launch_bounds__(256) void rmsnorm_kernel(
    const float* __restrict__ x, const float* __restrict__ w,
    float* __restrict__ xn) {
  const int b = blockIdx.x;
  const float* xr = x + (size_t)b * D_MODEL;
  float ss = 0.f;
  for (int i = threadIdx.x; i < D_MODEL; i += 256) {
    float v = xr[i];
    ss += v * v;
  }
#pragma unroll
  for (int off = 32; off > 0; off >>= 1) ss += __shfl_down(ss, off, 64);
  __shared__ float red[4];
  if ((threadIdx.x & 63) == 0) red[threadIdx.x >> 6] = ss;
  __syncthreads();
  const float tot = red[0] + red[1] + red[2] + red[3];
  const float scale = rsqrtf(tot * (1.f / (float)D_MODEL) + 1e-5f);
  float* xnr = xn + (size_t)b * D_MODEL;
  for (int i = threadIdx.x; i < D_MODEL; i += 256) xnr[i] = xr[i] * scale * w[i];
}

// ---------------------------------------------------------------------------
// Conv window + SiLU; writes inputs_new into flat_new. One thread per (b, e).
// ---------------------------------------------------------------------------
__global__ __launch_bounds__(256) void conv_silu_kernel(
    const float* __restrict__ flat_state, const float* __restrict__ xz,
    const float* __restrict__ conv_w, const float* __restrict__ conv_b,
    float* __restrict__ xs, float* __restrict__ outFlat) {
  const int id = blockIdx.x * 256 + threadIdx.x;
  const int b = id >> 11;
  const int e = id & (ED - 1);
  const float* inp = flat_state + (size_t)b * ROW_STATE + FLAT_H + e * 3;
  const float i0 = inp[0], i1 = inp[1], i2 = inp[2];
  const float x1 = xz[(size_t)b * (2 * ED) + e];
  const float* cw = conv_w + e * 4;
  const float xc = i0 * cw[0] + i1 * cw[1] + i2 * cw[2] + x1 * cw[3] + conv_b[e];
  xs[(size_t)b * ED + e] = xc * sigmoidf_(xc);
  float* on = outFlat + (size_t)b * ROW_STATE + FLAT_H + e * 3;
  on[0] = i1;
  on[1] = i2;
  on[2] = x1;
}

// ---------------------------------------------------------------------------
// SSM state update. One thread per (b, e).
// ---------------------------------------------------------------------------
__global__ __launch_bounds__(256) void state_kernel(
    const float* __restrict__ flat_state, const float* __restrict__ xz,
    const float* __restrict__ xs, const float* __restrict__ dbc,
    const float* __restrict__ delta, const float* __restrict__ A_log,
    const float* __restrict__ D_param, float* __restrict__ outFlat,
    float* __restrict__ yz) {
  const int id = blockIdx.x * 256 + threadIdx.x;
  const int b = id >> 11;
  const int e = id & (ED - 1);
  const float d = delta[(size_t)b * ED + e];
  const float xsv = xs[(size_t)b * ED + e];
  const float* hb = flat_state + (size_t)b * ROW_STATE + e * NSTATE;
  float* ho = outFlat + (size_t)b * ROW_STATE + e * NSTATE;
  const float* dbcb = dbc + (size_t)b * 96;
  const float* al = A_log + e * NSTATE;
  float y = 0.f;
#pragma unroll
  for (int n = 0; n < NSTATE; n++) {
    const float Aen = -expf(al[n]);
    const float dA = expf(d * Aen);
    const float hn = dA * hb[n] + d * dbcb[DTDIM + n] * xsv;
    ho[n] = hn;
    y += hn * dbcb[DTDIM + NSTATE + n];
  }
  y += D_param[e] * xsv;
  const float z = xz[(size_t)b * (2 * ED) + ED + e];
  yz[(size_t)b * ED + e] = y * (z * sigmoidf_(z));
}

extern "C" void kernel_launch(void* const* d_in, const int* in_sizes, int n_in,
                              void* d_out, int out_size, void* d_ws, size_t ws_size,
                              hipStream_t stream) {
  const float* x_t       = (const float*)d_in[0];
  const float* flat_state= (const float*)d_in[1];
  const float* W_in_cell = (const float*)d_in[2];
  const float* norm_w    = (const float*)d_in[3];
  const float* W_in      = (const float*)d_in[4];
  const float* conv_w    = (const float*)d_in[5];
  const float* conv_b    = (const float*)d_in[6];
  const float* W_xproj   = (const float*)d_in[7];
  const float* W_dt      = (const float*)d_in[8];
  const float* b_dt      = (const float*)d_in[9];
  const float* A_log     = (const float*)d_in[10];
  const float* D_param   = (const float*)d_in[11];
  const float* W_out     = (const float*)d_in[12];

  float* y_t_out = (float*)d_out;                       // B x D_MODEL
  float* outFlat = (float*)d_out + (size_t)B * D_MODEL; // B x ROW_STATE

  float* ws = (float*)d_ws;
  float* x     = ws;                                    // B x D_MODEL (residual)
  float* xn    = x + (size_t)B * D_MODEL;               // B x D_MODEL
  float* xz    = xn + (size_t)B * D_MODEL;              // B x 2ED
  float* xs    = xz + (size_t)B * 2 * ED;               // B x ED
  float* dbc   = xs + (size_t)B * ED;                   // B x 96
  float* delta = dbc + (size_t)B * 96;                  // B x ED
  float* yz    = delta + (size_t)B * ED;                // B x ED

  dim3 blk(256);

  // zero dbc for split-K atomic accumulation
  hipMemsetAsync(dbc, 0, (size_t)B * 96 * sizeof(float), stream);

  // 1) x = x_t @ W_in_cell^T                        (MFMA split-bf16)
  gemm_nt_mfma<0><<<dim3(D_MODEL / 128, B / 128), blk, 0, stream>>>(
      x_t, W_in_cell, x, B, D_MODEL, D_IN, D_IN, D_IN, D_MODEL, nullptr);
  // 2) xn = rmsnorm(x) * norm_w
  rmsnorm_kernel<<<dim3(B), blk, 0, stream>>>(x, norm_w, xn);
  // 3) xz = xn @ W_in^T                             (MFMA split-bf16)
  gemm_nt_mfma<0><<<dim3(2 * ED / 128, B / 128), blk, 0, stream>>>(
      xn, W_in, xz, B, 2 * ED, D_MODEL, D_MODEL, D_MODEL, 2 * ED, nullptr);
  // 4) conv + silu -> xs ; inputs_new -> flat_new
  conv_silu_kernel<<<dim3((B * ED) / 256), blk, 0, stream>>>(
      flat_state, xz, conv_w, conv_b, xs, outFlat);
  // 5) dbc = xs @ W_xproj^T                         (scalar, split-K x4, atomic)
  gemm_nt_splitk<<<dim3(2, B / 64, 4), blk, 0, stream>>>(
      xs, W_xproj, dbc, B, 96, ED, ED, ED, 96);
  // 6) delta = softplus(dbc[:, :64] @ W_dt^T + b_dt)  (MFMA split-bf16)
  gemm_nt_mfma<1><<<dim3(ED / 128, B / 128), blk, 0, stream>>>(
      dbc, W_dt, delta, B, ED, DTDIM, 96, DTDIM, ED, b_dt);
  // 7) state update -> h_new (flat_new), yz
  state_kernel<<<dim3((B * ED) / 256), blk, 0, stream>>>(
      flat_state, xz, xs, dbc, delta, A_log, D_param, outFlat, yz);
  // 8) y_t = yz @ W_out^T + residual                (MFMA split-bf16)
  gemm_nt_mfma<2><<<dim3(D_MODEL / 128, B / 128), blk, 0, stream>>>(
      yz, W_out, y_t_out, B, D_MODEL, ED, ED, ED, D_MODEL, x);
}

// Round 3
// 909.702 us; speedup vs baseline: 1.6684x; 1.1101x over previous
//
#include <hip/hip_runtime.h>
#include <math.h>

#define B 2048
#define D_IN 512
#define D_MODEL 1024
#define ED 2048
#define NSTATE 16
#define KCONV 4
#define DTDIM 64
#define FLAT_H (ED * NSTATE)                    /* 32768 */
#define ROW_STATE (FLAT_H + ED * (KCONV - 1))   /* 38912 */

typedef __attribute__((ext_vector_type(8))) short short8;   // 8 x bf16 (4 VGPRs)
typedef __attribute__((ext_vector_type(4))) short short4v;  // 4 x bf16 (8B)
typedef __attribute__((ext_vector_type(4))) float f32x4;

__device__ __forceinline__ float sigmoidf_(float x) { return 1.f / (1.f + expf(-x)); }

// round-to-nearest-even fp32 -> bf16 bits
__device__ __forceinline__ unsigned short f2bf(float f) {
  unsigned u = __float_as_uint(f);
  u += 0x7FFFu + ((u >> 16) & 1u);
  return (unsigned short)(u >> 16);
}
__device__ __forceinline__ float bf2f(unsigned short h) {
  return __uint_as_float((unsigned)h << 16);
}

// ---------------------------------------------------------------------------
// Split-bf16 MFMA NT-GEMM: C[m,n] = sum_k A[m,k] * W[n,k]  (+ epilogue)
// fp32 precision via a = a_hi + a_lo (both bf16): hi*hi + hi*lo + lo*hi.
// 128x128 tile, BK=32, 256 threads = 4 waves (2x2), each wave 64x64 via
// 4x4 frags of v_mfma_f32_16x16x32_bf16.
// REQUIRES: M%128==0, N%128==0, K%32==0, row strides %4==0.
// MODE 0: plain store   MODE 1: softplus(v + extra[n])   MODE 2: v + extra[m*ldc+n]
// ---------------------------------------------------------------------------
template <int MODE>
__global__ __launch_bounds__(256) void gemm_nt_mfma(
    const float* __restrict__ A, const float* __restrict__ W,
    float* __restrict__ C, int M, int N, int K, int lda, int ldw, int ldc,
    const float* __restrict__ extra) {
  __shared__ short Ahi[4][128][8];
  __shared__ short Alo[4][128][8];
  __shared__ short Whi[4][128][8];
  __shared__ short Wlo[4][128][8];

  const int tid = threadIdx.x;
  const int lane = tid & 63;
  const int wave = tid >> 6;      // 0..3
  const int wr = wave >> 1;       // wave row (m)  0..1
  const int wc = wave & 1;        // wave col (n)  0..1
  const int m0 = blockIdx.y * 128;
  const int n0 = blockIdx.x * 128;
  const int kg = lane >> 4;       // k-group 0..3
  const int lr = lane & 15;       // row/col within frag

  f32x4 acc[4][4] = {};

  for (int k0 = 0; k0 < K; k0 += 32) {
#pragma unroll
    for (int it = 0; it < 4; ++it) {
      const int flat = tid + it * 256;   // 0..1023
      const int row = flat >> 3;         // 0..127
      const int kq = flat & 7;           // k-quad 0..7
      const int tkg = kq >> 1;
      const int j0 = (kq & 1) * 4;
      const float4 av = *(const float4*)(A + (size_t)(m0 + row) * lda + (k0 + kq * 4));
      const float4 wv = *(const float4*)(W + (size_t)(n0 + row) * ldw + (k0 + kq * 4));
      const float af[4] = {av.x, av.y, av.z, av.w};
      const float wf[4] = {wv.x, wv.y, wv.z, wv.w};
      short4v ah, al, wh, wl;
#pragma unroll
      for (int e = 0; e < 4; ++e) {
        const unsigned short h = f2bf(af[e]);
        ah[e] = (short)h;
        al[e] = (short)f2bf(af[e] - bf2f(h));
        const unsigned short hw = f2bf(wf[e]);
        wh[e] = (short)hw;
        wl[e] = (short)f2bf(wf[e] - bf2f(hw));
      }
      *(short4v*)&Ahi[tkg][row][j0] = ah;
      *(short4v*)&Alo[tkg][row][j0] = al;
      *(short4v*)&Whi[tkg][row][j0] = wh;
      *(short4v*)&Wlo[tkg][row][j0] = wl;
    }
    __syncthreads();

    short8 a_h[4], a_l[4], b_h[4], b_l[4];
#pragma unroll
    for (int i = 0; i < 4; ++i) {
      a_h[i] = *(const short8*)&Ahi[kg][wr * 64 + i * 16 + lr][0];
      a_l[i] = *(const short8*)&Alo[kg][wr * 64 + i * 16 + lr][0];
      b_h[i] = *(const short8*)&Whi[kg][wc * 64 + i * 16 + lr][0];
      b_l[i] = *(const short8*)&Wlo[kg][wc * 64 + i * 16 + lr][0];
    }
#pragma unroll
    for (int i = 0; i < 4; ++i)
#pragma unroll
      for (int j = 0; j < 4; ++j) {
        acc[i][j] = __builtin_amdgcn_mfma_f32_16x16x32_bf16(a_h[i], b_h[j], acc[i][j], 0, 0, 0);
        acc[i][j] = __builtin_amdgcn_mfma_f32_16x16x32_bf16(a_l[i], b_h[j], acc[i][j], 0, 0, 0);
        acc[i][j] = __builtin_amdgcn_mfma_f32_16x16x32_bf16(a_h[i], b_l[j], acc[i][j], 0, 0, 0);
      }
    __syncthreads();
  }

#pragma unroll
  for (int i = 0; i < 4; ++i) {
    const int gm = m0 + wr * 64 + i * 16 + kg * 4;
#pragma unroll
    for (int j = 0; j < 4; ++j) {
      const int gn = n0 + wc * 64 + j * 16 + lr;
#pragma unroll
      for (int r = 0; r < 4; ++r) {
        float v = acc[i][j][r];
        if (MODE == 1) {
          v += extra[gn];
          v = (v > 20.f) ? v : log1pf(expf(v));
        } else if (MODE == 2) {
          v += extra[(size_t)(gm + r) * ldc + gn];
        }
        C[(size_t)(gm + r) * ldc + gn] = v;
      }
    }
  }
}

// ---------------------------------------------------------------------------
// Scalar fp32 NT-GEMM with split-K (grid.z), atomicAdd accumulate.
// Used only for dbc (N=96). C must be pre-zeroed.
// ---------------------------------------------------------------------------
__global__ __launch_bounds__(256) void gemm_nt_splitk(
    const float* __restrict__ A, const float* __restrict__ W,
    float* __restrict__ C, int M, int N, int K, int lda, int ldw, int ldc) {
  __shared__ float As[16][68];
  __shared__ float Ws[16][68];
  const int tid = threadIdx.x;
  const int tx = tid & 15;
  const int ty = tid >> 4;
  const int m0 = blockIdx.y * 64;
  const int n0 = blockIdx.x * 64;
  const int kchunk = K / gridDim.z;
  const int kbeg = blockIdx.z * kchunk;

  float acc[4][4] = {};
  const int lr = tid >> 4;
  const int lc = tid & 15;

  for (int k0 = kbeg; k0 < kbeg + kchunk; k0 += 16) {
#pragma unroll
    for (int i = 0; i < 4; i++) {
      const int r = lr + i * 16;
      const int gk = k0 + lc;
      As[lc][r] = A[(size_t)(m0 + r) * lda + gk];
      const int gn = n0 + r;
      Ws[lc][r] = (gn < N) ? W[(size_t)gn * ldw + gk] : 0.f;
    }
    __syncthreads();
#pragma unroll
    for (int k = 0; k < 16; k++) {
      float a[4], w[4];
#pragma unroll
      for (int i = 0; i < 4; i++) a[i] = As[k][ty * 4 + i];
#pragma unroll
      for (int j = 0; j < 4; j++) w[j] = Ws[k][tx * 4 + j];
#pragma unroll
      for (int i = 0; i < 4; i++)
#pragma unroll
        for (int j = 0; j < 4; j++) acc[i][j] += a[i] * w[j];
    }
    __syncthreads();
  }

#pragma unroll
  for (int i = 0; i < 4; i++) {
    const int gm = m0 + ty * 4 + i;
#pragma unroll
    for (int j = 0; j < 4; j++) {
      const int gn = n0 + tx * 4 + j;
      if (gn >= N) continue;
      atomicAdd(&C[(size_t)gm * ldc + gn], acc[i][j]);
    }
  }
}

// ---------------------------------------------------------------------------
// RMSNorm (vectorized): one block per row, 256 threads x float4 = 1024 elems.
// ---------------------------------------------------------------------------
__global__ __launch_bounds__(256) void rmsnorm_kernel(
    const float* __restrict__ x, const float* __restrict__ w,
    float* __restrict__ xn) {
  const int b = blockIdx.x;
  const int i4 = threadIdx.x * 4;
  const float4 v = *(const float4*)(x + (size_t)b * D_MODEL + i4);
  float ss = v.x * v.x + v.y * v.y + v.z * v.z + v.w * v.w;
#pragma unroll
  for (int off = 32; off > 0; off >>= 1) ss += __shfl_down(ss, off, 64);
  __shared__ float red[4];
  if ((threadIdx.x & 63) == 0) red[threadIdx.x >> 6] = ss;
  __syncthreads();
  const float tot = red[0] + red[1] + red[2] + red[3];
  const float scale = rsqrtf(tot * (1.f / (float)D_MODEL) + 1e-5f);
  const float4 wv = *(const float4*)(w + i4);
  float4 o;
  o.x = v.x * scale * wv.x;
  o.y = v.y * scale * wv.y;
  o.z = v.z * scale * wv.z;
  o.w = v.w * scale * wv.w;
  *(float4*)(xn + (size_t)b * D_MODEL + i4) = o;
}

// ---------------------------------------------------------------------------
// Aneg = -exp(A_log), precomputed once (ED*NSTATE = 32768 elems).
// ---------------------------------------------------------------------------
__global__ __launch_bounds__(256) void prep_aneg(
    const float* __restrict__ A_log, float* __restrict__ Aneg) {
  const int i4 = (blockIdx.x * 256 + threadIdx.x) * 4;
  const float4 v = *(const float4*)(A_log + i4);
  float4 o;
  o.x = -expf(v.x);
  o.y = -expf(v.y);
  o.z = -expf(v.z);
  o.w = -expf(v.w);
  *(float4*)(Aneg + i4) = o;
}

// ---------------------------------------------------------------------------
// Conv window + SiLU, one block per batch row. Window staged in LDS with
// coalesced float4 loads; shifted window written back coalesced.
// ---------------------------------------------------------------------------
__global__ __launch_bounds__(256) void conv_silu_kernel(
    const float* __restrict__ flat_state, const float* __restrict__ xz,
    const float* __restrict__ conv_w, const float* __restrict__ conv_b,
    float* __restrict__ xs, float* __restrict__ outFlat) {
  const int b = blockIdx.x;
  __shared__ float sin_[ED * 3];   // 24 KB
  __shared__ float sx1[ED];        // 8 KB
  const float* inRow = flat_state + (size_t)b * ROW_STATE + FLAT_H;
  const float* x1Row = xz + (size_t)b * (2 * ED);
#pragma unroll
  for (int i = 0; i < 6; ++i) {
    const int idx = (threadIdx.x + i * 256) * 4;
    *(float4*)&sin_[idx] = *(const float4*)&inRow[idx];
  }
#pragma unroll
  for (int i = 0; i < 2; ++i) {
    const int idx = (threadIdx.x + i * 256) * 4;
    *(float4*)&sx1[idx] = *(const float4*)&x1Row[idx];
  }
  __syncthreads();
  float* xsRow = xs + (size_t)b * ED;
#pragma unroll
  for (int k = 0; k < 8; ++k) {
    const int e = threadIdx.x + k * 256;
    const float4 cw = *(const float4*)(conv_w + e * 4);
    const float xc = sin_[e * 3] * cw.x + sin_[e * 3 + 1] * cw.y +
                     sin_[e * 3 + 2] * cw.z + sx1[e] * cw.w + conv_b[e];
    xsRow[e] = xc * sigmoidf_(xc);
  }
  float* on = outFlat + (size_t)b * ROW_STATE + FLAT_H;
#pragma unroll
  for (int k = 0; k < 24; ++k) {
    const int i = threadIdx.x + k * 256;
    const int q = i / 3;
    const int r = i - q * 3;
    on[i] = (r == 2) ? sx1[q] : sin_[i + 1];
  }
}

// ---------------------------------------------------------------------------
// SSM state update, fully coalesced: each thread owns 4 consecutive floats of
// the flattened h row (e = off>>4, n0 = off&15 in {0,4,8,12}). y-reduction via
// 2-step shfl_xor across the 4 lanes sharing an e.
// ---------------------------------------------------------------------------
__global__ __launch_bounds__(256) void state_kernel(
    const float* __restrict__ flat_state, const float* __restrict__ xz,
    const float* __restrict__ xs, const float* __restrict__ dbc,
    const float* __restrict__ delta, const float* __restrict__ Aneg,
    const float* __restrict__ D_param, float* __restrict__ outFlat,
    float* __restrict__ yz) {
  const int id = blockIdx.x * 256 + threadIdx.x;
  const int f = id << 2;            // flat index into (b, e*16+n)
  const int b = f >> 15;            // 32768 h-floats per b
  const int off = f & 32767;        // e*16 + n0
  const int e = off >> 4;
  const int n0 = off & 15;          // 0,4,8,12

  const float d = delta[(size_t)b * ED + e];
  const float xsv = xs[(size_t)b * ED + e];
  const float dx = d * xsv;
  const float4 h4 = *(const float4*)(flat_state + (size_t)b * ROW_STATE + off);
  const float4 a4 = *(const float4*)(Aneg + off);
  const float* dbcb = dbc + (size_t)b * 96;
  const float4 B4 = *(const float4*)(dbcb + DTDIM + n0);
  const float4 C4 = *(const float4*)(dbcb + DTDIM + NSTATE + n0);

  float4 hn;
  hn.x = expf(d * a4.x) * h4.x + dx * B4.x;
  hn.y = expf(d * a4.y) * h4.y + dx * B4.y;
  hn.z = expf(d * a4.z) * h4.z + dx * B4.z;
  hn.w = expf(d * a4.w) * h4.w + dx * B4.w;
  *(float4*)(outFlat + (size_t)b * ROW_STATE + off) = hn;

  float y = hn.x * C4.x + hn.y * C4.y + hn.z * C4.z + hn.w * C4.w;
  y += __shfl_xor(y, 1, 64);
  y += __shfl_xor(y, 2, 64);
  if (n0 == 0) {
    y += D_param[e] * xsv;
    const float z = xz[(size_t)b * (2 * ED) + ED + e];
    yz[(size_t)b * ED + e] = y * (z * sigmoidf_(z));
  }
}

extern "C" void kernel_launch(void* const* d_in, const int* in_sizes, int n_in,
                              void* d_out, int out_size, void* d_ws, size_t ws_size,
                              hipStream_t stream) {
  const float* x_t       = (const float*)d_in[0];
  const float* flat_state= (const float*)d_in[1];
  const float* W_in_cell = (const float*)d_in[2];
  const float* norm_w    = (const float*)d_in[3];
  const float* W_in      = (const float*)d_in[4];
  const float* conv_w    = (const float*)d_in[5];
  const float* conv_b    = (const float*)d_in[6];
  const float* W_xproj   = (const float*)d_in[7];
  const float* W_dt      = (const float*)d_in[8];
  const float* b_dt      = (const float*)d_in[9];
  const float* A_log     = (const float*)d_in[10];
  const float* D_param   = (const float*)d_in[11];
  const float* W_out     = (const float*)d_in[12];

  float* y_t_out = (float*)d_out;                       // B x D_MODEL
  float* outFlat = (float*)d_out + (size_t)B * D_MODEL; // B x ROW_STATE

  float* ws = (float*)d_ws;
  float* x     = ws;                                    // B x D_MODEL (residual)
  float* xn    = x + (size_t)B * D_MODEL;               // B x D_MODEL
  float* xz    = xn + (size_t)B * D_MODEL;              // B x 2ED
  float* xs    = xz + (size_t)B * 2 * ED;               // B x ED
  float* dbc   = xs + (size_t)B * ED;                   // B x 96
  float* delta = dbc + (size_t)B * 96;                  // B x ED
  float* yz    = delta + (size_t)B * ED;                // B x ED
  // Aneg aliases xn (dead after step 3); prep_aneg runs after step 3.
  float* Aneg  = xn;

  dim3 blk(256);

  // zero dbc for split-K atomic accumulation
  (void)hipMemsetAsync(dbc, 0, (size_t)B * 96 * sizeof(float), stream);

  // 1) x = x_t @ W_in_cell^T                        (MFMA split-bf16)
  gemm_nt_mfma<0><<<dim3(D_MODEL / 128, B / 128), blk, 0, stream>>>(
      x_t, W_in_cell, x, B, D_MODEL, D_IN, D_IN, D_IN, D_MODEL, nullptr);
  // 2) xn = rmsnorm(x) * norm_w
  rmsnorm_kernel<<<dim3(B), blk, 0, stream>>>(x, norm_w, xn);
  // 3) xz = xn @ W_in^T                             (MFMA split-bf16)
  gemm_nt_mfma<0><<<dim3(2 * ED / 128, B / 128), blk, 0, stream>>>(
      xn, W_in, xz, B, 2 * ED, D_MODEL, D_MODEL, D_MODEL, 2 * ED, nullptr);
  // 3b) Aneg = -exp(A_log)  (xn is dead now; reuse its space)
  prep_aneg<<<dim3(ED * NSTATE / 1024), blk, 0, stream>>>(A_log, Aneg);
  // 4) conv + silu -> xs ; inputs_new -> flat_new
  conv_silu_kernel<<<dim3(B), blk, 0, stream>>>(
      flat_state, xz, conv_w, conv_b, xs, outFlat);
  // 5) dbc = xs @ W_xproj^T                         (scalar, split-K x8, atomic)
  gemm_nt_splitk<<<dim3(2, B / 64, 8), blk, 0, stream>>>(
      xs, W_xproj, dbc, B, 96, ED, ED, ED, 96);
  // 6) delta = softplus(dbc[:, :64] @ W_dt^T + b_dt)  (MFMA split-bf16)
  gemm_nt_mfma<1><<<dim3(ED / 128, B / 128), blk, 0, stream>>>(
      dbc, W_dt, delta, B, ED, DTDIM, 96, DTDIM, ED, b_dt);
  // 7) state update -> h_new (flat_new), yz
  state_kernel<<<dim3((size_t)B * FLAT_H / 1024), blk, 0, stream>>>(
      flat_state, xz, xs, dbc, delta, Aneg, D_param, outFlat, yz);
  // 8) y_t = yz @ W_out^T + residual                (MFMA split-bf16)
  gemm_nt_mfma<2><<<dim3(D_MODEL / 128, B / 128), blk, 0, stream>>>(
      yz, W_out, y_t_out, B, D_MODEL, ED, ED, ED, D_MODEL, x);
}

// Round 5
// 851.850 us; speedup vs baseline: 1.7817x; 1.0679x over previous
//
#include <hip/hip_runtime.h>
#include <math.h>

#define B 2048
#define D_IN 512
#define D_MODEL 1024
#define ED 2048
#define NSTATE 16
#define KCONV 4
#define DTDIM 64
#define FLAT_H (ED * NSTATE)                    /* 32768 */
#define ROW_STATE (FLAT_H + ED * (KCONV - 1))   /* 38912 */

typedef __attribute__((ext_vector_type(8))) short short8;   // 8 x bf16 (4 VGPRs)
typedef __attribute__((ext_vector_type(4))) short short4v;  // 4 x bf16 (8B)
typedef __attribute__((ext_vector_type(4))) float f32x4;
typedef unsigned short ushort_t;

__device__ __forceinline__ float sigmoidf_(float x) { return 1.f / (1.f + expf(-x)); }

// round-to-nearest-even fp32 -> bf16 bits
__device__ __forceinline__ unsigned short f2bf(float f) {
  unsigned u = __float_as_uint(f);
  u += 0x7FFFu + ((u >> 16) & 1u);
  return (unsigned short)(u >> 16);
}
__device__ __forceinline__ float bf2f(unsigned short h) {
  return __uint_as_float((unsigned)h << 16);
}
struct hl_t { short h, l; };
__device__ __forceinline__ hl_t split2(float f) {
  hl_t r;
  const unsigned short hu = f2bf(f);
  r.h = (short)hu;
  r.l = (short)f2bf(f - bf2f(hu));
  return r;
}

// async global->LDS, 16B per lane; LDS dest = uniform base + lane*16
__device__ __forceinline__ void gload_lds16(const void* g, void* l) {
  __builtin_amdgcn_global_load_lds(
      (const __attribute__((address_space(1))) void*)g,
      (__attribute__((address_space(3))) void*)l, 16, 0, 0);
}

// ---------------------------------------------------------------------------
// Pre-split bf16 MFMA NT-GEMM: C = A @ W^T with A,W given as bf16 hi/lo pairs
// (row-major [M][K] / [N][K] ushort). fp32 precision via hi*hi + lo*hi + hi*lo.
// 128x128 tile, BK=32, 256 threads = 4 waves (2x2), 4x4 frags of
// v_mfma_f32_16x16x32_bf16 per wave. Staging via global_load_lds width 16
// into XOR-swizzled LDS (slot = chunk ^ (row&7)) -> conflict-free ds_read_b128.
// REQUIRES: M%128==0, N%128==0, K%32==0.
// MODE 0: plain store   MODE 2: v + extra[m*ldc+n]
// ---------------------------------------------------------------------------
template <int MODE>
__global__ __launch_bounds__(256) void gemm_bs(
    const ushort_t* __restrict__ Ahi, const ushort_t* __restrict__ Alo,
    const ushort_t* __restrict__ Whi, const ushort_t* __restrict__ Wlo,
    float* __restrict__ C, int M, int N, int K, int ldc,
    const float* __restrict__ extra) {
  // lds[side][row][64]: row = 128 B = 8 slots of 16 B. slot s of row holds
  // chunk c = s ^ (row&7), c = mat*4 + kq (mat 0=hi 1=lo, kq = k-octet).
  __shared__ ushort_t lds[2][128][64];

  const int tid = threadIdx.x;
  const int lane = tid & 63;
  const int w = tid >> 6;         // wave 0..3
  const int wr = w >> 1;          // wave row (m)
  const int wc = w & 1;           // wave col (n)
  const int m0 = blockIdx.y * 128;
  const int n0 = blockIdx.x * 128;
  const int kg = lane >> 4;       // k-group 0..3
  const int lr = lane & 15;

  // staging lane constants
  const int srow = lane >> 3;     // row within 8-row block
  const int sslot = lane & 7;     // LDS slot
  const int c = sslot ^ srow;     // stored chunk (pre-swizzled global source)
  const int mat = c >> 2;         // 0=hi, 1=lo
  const int kq8 = (c & 3) * 8;    // k element offset of chunk

  const int side = w >> 1;        // waves 0,1 stage A; waves 2,3 stage W
  const ushort_t* hiP = side ? Whi : Ahi;
  const ushort_t* loP = side ? Wlo : Alo;
  const ushort_t* matP = mat ? loP : hiP;
  const int base0 = side ? n0 : m0;

  f32x4 acc[4][4] = {};

  for (int k0 = 0; k0 < K; k0 += 32) {
    // ---- stage: 8 global_load_lds (1 KB each) per wave ----
#pragma unroll
    for (int t = 0; t < 8; ++t) {
      const int rb = (w & 1) * 8 + t;          // rowblock 0..15
      const int row = rb * 8 + srow;           // row&7 == srow
      const ushort_t* g = matP + (size_t)(base0 + row) * K + k0 + kq8;
      gload_lds16(g, &lds[side][rb * 8][0]);
    }
    __syncthreads();

    // ---- fragments (swizzled slot addressing) + MFMA ----
    short8 a_h[4], a_l[4], b_h[4], b_l[4];
#pragma unroll
    for (int i = 0; i < 4; ++i) {
      const int r = wr * 64 + i * 16 + lr;
      const int r7 = r & 7;
      a_h[i] = *(const short8*)&lds[0][r][(kg ^ r7) * 8];
      a_l[i] = *(const short8*)&lds[0][r][((4 + kg) ^ r7) * 8];
      const int rr = wc * 64 + i * 16 + lr;
      const int rr7 = rr & 7;
      b_h[i] = *(const short8*)&lds[1][rr][(kg ^ rr7) * 8];
      b_l[i] = *(const short8*)&lds[1][rr][((4 + kg) ^ rr7) * 8];
    }
#pragma unroll
    for (int i = 0; i < 4; ++i)
#pragma unroll
      for (int j = 0; j < 4; ++j) {
        acc[i][j] = __builtin_amdgcn_mfma_f32_16x16x32_bf16(a_h[i], b_h[j], acc[i][j], 0, 0, 0);
        acc[i][j] = __builtin_amdgcn_mfma_f32_16x16x32_bf16(a_l[i], b_h[j], acc[i][j], 0, 0, 0);
        acc[i][j] = __builtin_amdgcn_mfma_f32_16x16x32_bf16(a_h[i], b_l[j], acc[i][j], 0, 0, 0);
      }
    __syncthreads();
  }

  // ---- epilogue: C/D layout col = lane&15, row = (lane>>4)*4 + reg ----
#pragma unroll
  for (int i = 0; i < 4; ++i) {
    const int gm = m0 + wr * 64 + i * 16 + kg * 4;
#pragma unroll
    for (int j = 0; j < 4; ++j) {
      const int gn = n0 + wc * 64 + j * 16 + lr;
#pragma unroll
      for (int r = 0; r < 4; ++r) {
        float v = acc[i][j][r];
        if (MODE == 2) v += extra[(size_t)(gm + r) * ldc + gn];
        C[(size_t)(gm + r) * ldc + gn] = v;
      }
    }
  }
}

// ---------------------------------------------------------------------------
// Elementwise fp32 -> (hi,lo) bf16 split. n must be multiple of 1024.
// ---------------------------------------------------------------------------
__global__ __launch_bounds__(256) void split_kernel(
    const float* __restrict__ in, ushort_t* __restrict__ hi,
    ushort_t* __restrict__ lo) {
  const int i4 = (blockIdx.x * 256 + threadIdx.x) * 4;
  const float4 v = *(const float4*)(in + i4);
  short4v h, l;
  hl_t s0 = split2(v.x), s1 = split2(v.y), s2 = split2(v.z), s3 = split2(v.w);
  h[0] = s0.h; l[0] = s0.l;
  h[1] = s1.h; l[1] = s1.l;
  h[2] = s2.h; l[2] = s2.l;
  h[3] = s3.h; l[3] = s3.l;
  *(short4v*)(hi + i4) = h;
  *(short4v*)(lo + i4) = l;
}

// ---------------------------------------------------------------------------
// Legacy split-bf16 GEMM with in-loop conversion (kept for delta: K=64, tiny).
// MODE 1: softplus(v + extra[n])
// ---------------------------------------------------------------------------
template <int MODE>
__global__ __launch_bounds__(256) void gemm_nt_mfma(
    const float* __restrict__ A, const float* __restrict__ W,
    float* __restrict__ C, int M, int N, int K, int lda, int ldw, int ldc,
    const float* __restrict__ extra) {
  __shared__ short Ahi[4][128][8];
  __shared__ short Alo[4][128][8];
  __shared__ short Whi[4][128][8];
  __shared__ short Wlo[4][128][8];

  const int tid = threadIdx.x;
  const int lane = tid & 63;
  const int wave = tid >> 6;
  const int wr = wave >> 1;
  const int wc = wave & 1;
  const int m0 = blockIdx.y * 128;
  const int n0 = blockIdx.x * 128;
  const int kg = lane >> 4;
  const int lr = lane & 15;

  f32x4 acc[4][4] = {};

  for (int k0 = 0; k0 < K; k0 += 32) {
#pragma unroll
    for (int it = 0; it < 4; ++it) {
      const int flat = tid + it * 256;
      const int row = flat >> 3;
      const int kq = flat & 7;
      const int tkg = kq >> 1;
      const int j0 = (kq & 1) * 4;
      const float4 av = *(const float4*)(A + (size_t)(m0 + row) * lda + (k0 + kq * 4));
      const float4 wv = *(const float4*)(W + (size_t)(n0 + row) * ldw + (k0 + kq * 4));
      const float af[4] = {av.x, av.y, av.z, av.w};
      const float wf[4] = {wv.x, wv.y, wv.z, wv.w};
      short4v ah, al, wh, wl;
#pragma unroll
      for (int e = 0; e < 4; ++e) {
        hl_t sa = split2(af[e]);
        ah[e] = sa.h; al[e] = sa.l;
        hl_t sw = split2(wf[e]);
        wh[e] = sw.h; wl[e] = sw.l;
      }
      *(short4v*)&Ahi[tkg][row][j0] = ah;
      *(short4v*)&Alo[tkg][row][j0] = al;
      *(short4v*)&Whi[tkg][row][j0] = wh;
      *(short4v*)&Wlo[tkg][row][j0] = wl;
    }
    __syncthreads();

    short8 a_h[4], a_l[4], b_h[4], b_l[4];
#pragma unroll
    for (int i = 0; i < 4; ++i) {
      a_h[i] = *(const short8*)&Ahi[kg][wr * 64 + i * 16 + lr][0];
      a_l[i] = *(const short8*)&Alo[kg][wr * 64 + i * 16 + lr][0];
      b_h[i] = *(const short8*)&Whi[kg][wc * 64 + i * 16 + lr][0];
      b_l[i] = *(const short8*)&Wlo[kg][wc * 64 + i * 16 + lr][0];
    }
#pragma unroll
    for (int i = 0; i < 4; ++i)
#pragma unroll
      for (int j = 0; j < 4; ++j) {
        acc[i][j] = __builtin_amdgcn_mfma_f32_16x16x32_bf16(a_h[i], b_h[j], acc[i][j], 0, 0, 0);
        acc[i][j] = __builtin_amdgcn_mfma_f32_16x16x32_bf16(a_l[i], b_h[j], acc[i][j], 0, 0, 0);
        acc[i][j] = __builtin_amdgcn_mfma_f32_16x16x32_bf16(a_h[i], b_l[j], acc[i][j], 0, 0, 0);
      }
    __syncthreads();
  }

#pragma unroll
  for (int i = 0; i < 4; ++i) {
    const int gm = m0 + wr * 64 + i * 16 + kg * 4;
#pragma unroll
    for (int j = 0; j < 4; ++j) {
      const int gn = n0 + wc * 64 + j * 16 + lr;
#pragma unroll
      for (int r = 0; r < 4; ++r) {
        float v = acc[i][j][r];
        if (MODE == 1) {
          v += extra[gn];
          v = (v > 20.f) ? v : log1pf(expf(v));
        }
        C[(size_t)(gm + r) * ldc + gn] = v;
      }
    }
  }
}

// ---------------------------------------------------------------------------
// Scalar fp32 NT-GEMM with split-K (grid.z), atomicAdd. Used for dbc (N=96).
// ---------------------------------------------------------------------------
__global__ __launch_bounds__(256) void gemm_nt_splitk(
    const float* __restrict__ A, const float* __restrict__ W,
    float* __restrict__ C, int M, int N, int K, int lda, int ldw, int ldc) {
  __shared__ float As[16][68];
  __shared__ float Ws[16][68];
  const int tid = threadIdx.x;
  const int tx = tid & 15;
  const int ty = tid >> 4;
  const int m0 = blockIdx.y * 64;
  const int n0 = blockIdx.x * 64;
  const int kchunk = K / gridDim.z;
  const int kbeg = blockIdx.z * kchunk;

  float acc[4][4] = {};
  const int lr = tid >> 4;
  const int lc = tid & 15;

  for (int k0 = kbeg; k0 < kbeg + kchunk; k0 += 16) {
#pragma unroll
    for (int i = 0; i < 4; i++) {
      const int r = lr + i * 16;
      const int gk = k0 + lc;
      As[lc][r] = A[(size_t)(m0 + r) * lda + gk];
      const int gn = n0 + r;
      Ws[lc][r] = (gn < N) ? W[(size_t)gn * ldw + gk] : 0.f;
    }
    __syncthreads();
#pragma unroll
    for (int k = 0; k < 16; k++) {
      float a[4], wv[4];
#pragma unroll
      for (int i = 0; i < 4; i++) a[i] = As[k][ty * 4 + i];
#pragma unroll
      for (int j = 0; j < 4; j++) wv[j] = Ws[k][tx * 4 + j];
#pragma unroll
      for (int i = 0; i < 4; i++)
#pragma unroll
        for (int j = 0; j < 4; j++) acc[i][j] += a[i] * wv[j];
    }
    __syncthreads();
  }

#pragma unroll
  for (int i = 0; i < 4; i++) {
    const int gm = m0 + ty * 4 + i;
#pragma unroll
    for (int j = 0; j < 4; j++) {
      const int gn = n0 + tx * 4 + j;
      if (gn >= N) continue;
      atomicAdd(&C[(size_t)gm * ldc + gn], acc[i][j]);
    }
  }
}

// ---------------------------------------------------------------------------
// RMSNorm fused with bf16 hi/lo split output (xn only feeds the xz GEMM).
// ---------------------------------------------------------------------------
__global__ __launch_bounds__(256) void rmsnorm_split_kernel(
    const float* __restrict__ x, const float* __restrict__ w,
    ushort_t* __restrict__ xn_hi, ushort_t* __restrict__ xn_lo) {
  const int b = blockIdx.x;
  const int i4 = threadIdx.x * 4;
  const float4 v = *(const float4*)(x + (size_t)b * D_MODEL + i4);
  float ss = v.x * v.x + v.y * v.y + v.z * v.z + v.w * v.w;
#pragma unroll
  for (int off = 32; off > 0; off >>= 1) ss += __shfl_down(ss, off, 64);
  __shared__ float red[4];
  if ((threadIdx.x & 63) == 0) red[threadIdx.x >> 6] = ss;
  __syncthreads();
  const float tot = red[0] + red[1] + red[2] + red[3];
  const float scale = rsqrtf(tot * (1.f / (float)D_MODEL) + 1e-5f);
  const float4 wv = *(const float4*)(w + i4);
  short4v h, l;
  hl_t s0 = split2(v.x * scale * wv.x);
  hl_t s1 = split2(v.y * scale * wv.y);
  hl_t s2 = split2(v.z * scale * wv.z);
  hl_t s3 = split2(v.w * scale * wv.w);
  h[0] = s0.h; l[0] = s0.l;
  h[1] = s1.h; l[1] = s1.l;
  h[2] = s2.h; l[2] = s2.l;
  h[3] = s3.h; l[3] = s3.l;
  *(short4v*)(xn_hi + (size_t)b * D_MODEL + i4) = h;
  *(short4v*)(xn_lo + (size_t)b * D_MODEL + i4) = l;
}

// ---------------------------------------------------------------------------
// Aneg = -exp(A_log), 32768 elems.
// ---------------------------------------------------------------------------
__global__ __launch_bounds__(256) void prep_aneg(
    const float* __restrict__ A_log, float* __restrict__ Aneg) {
  const int i4 = (blockIdx.x * 256 + threadIdx.x) * 4;
  const float4 v = *(const float4*)(A_log + i4);
  float4 o;
  o.x = -expf(v.x);
  o.y = -expf(v.y);
  o.z = -expf(v.z);
  o.w = -expf(v.w);
  *(float4*)(Aneg + i4) = o;
}

// ---------------------------------------------------------------------------
// Conv window + SiLU, one block per batch row (LDS-staged, coalesced).
// ---------------------------------------------------------------------------
__global__ __launch_bounds__(256) void conv_silu_kernel(
    const float* __restrict__ flat_state, const float* __restrict__ xz,
    const float* __restrict__ conv_w, const float* __restrict__ conv_b,
    float* __restrict__ xs, float* __restrict__ outFlat) {
  const int b = blockIdx.x;
  __shared__ float sin_[ED * 3];   // 24 KB
  __shared__ float sx1[ED];        // 8 KB
  const float* inRow = flat_state + (size_t)b * ROW_STATE + FLAT_H;
  const float* x1Row = xz + (size_t)b * (2 * ED);
#pragma unroll
  for (int i = 0; i < 6; ++i) {
    const int idx = (threadIdx.x + i * 256) * 4;
    *(float4*)&sin_[idx] = *(const float4*)&inRow[idx];
  }
#pragma unroll
  for (int i = 0; i < 2; ++i) {
    const int idx = (threadIdx.x + i * 256) * 4;
    *(float4*)&sx1[idx] = *(const float4*)&x1Row[idx];
  }
  __syncthreads();
  float* xsRow = xs + (size_t)b * ED;
#pragma unroll
  for (int k = 0; k < 8; ++k) {
    const int e = threadIdx.x + k * 256;
    const float4 cw = *(const float4*)(conv_w + e * 4);
    const float xc = sin_[e * 3] * cw.x + sin_[e * 3 + 1] * cw.y +
                     sin_[e * 3 + 2] * cw.z + sx1[e] * cw.w + conv_b[e];
    xsRow[e] = xc * sigmoidf_(xc);
  }
  float* on = outFlat + (size_t)b * ROW_STATE + FLAT_H;
#pragma unroll
  for (int k = 0; k < 24; ++k) {
    const int i = threadIdx.x + k * 256;
    const int q = i / 3;
    const int r = i - q * 3;
    on[i] = (r == 2) ? sx1[q] : sin_[i + 1];
  }
}

// ---------------------------------------------------------------------------
// SSM state update, fully coalesced float4.
// ---------------------------------------------------------------------------
__global__ __launch_bounds__(256) void state_kernel(
    const float* __restrict__ flat_state, const float* __restrict__ xz,
    const float* __restrict__ xs, const float* __restrict__ dbc,
    const float* __restrict__ delta, const float* __restrict__ Aneg,
    const float* __restrict__ D_param, float* __restrict__ outFlat,
    float* __restrict__ yz) {
  const int id = blockIdx.x * 256 + threadIdx.x;
  const int f = id << 2;
  const int b = f >> 15;
  const int off = f & 32767;
  const int e = off >> 4;
  const int n0 = off & 15;

  const float d = delta[(size_t)b * ED + e];
  const float xsv = xs[(size_t)b * ED + e];
  const float dx = d * xsv;
  const float4 h4 = *(const float4*)(flat_state + (size_t)b * ROW_STATE + off);
  const float4 a4 = *(const float4*)(Aneg + off);
  const float* dbcb = dbc + (size_t)b * 96;
  const float4 B4 = *(const float4*)(dbcb + DTDIM + n0);
  const float4 C4 = *(const float4*)(dbcb + DTDIM + NSTATE + n0);

  float4 hn;
  hn.x = expf(d * a4.x) * h4.x + dx * B4.x;
  hn.y = expf(d * a4.y) * h4.y + dx * B4.y;
  hn.z = expf(d * a4.z) * h4.z + dx * B4.z;
  hn.w = expf(d * a4.w) * h4.w + dx * B4.w;
  *(float4*)(outFlat + (size_t)b * ROW_STATE + off) = hn;

  float y = hn.x * C4.x + hn.y * C4.y + hn.z * C4.z + hn.w * C4.w;
  y += __shfl_xor(y, 1, 64);
  y += __shfl_xor(y, 2, 64);
  if (n0 == 0) {
    y += D_param[e] * xsv;
    const float z = xz[(size_t)b * (2 * ED) + ED + e];
    yz[(size_t)b * ED + e] = y * (z * sigmoidf_(z));
  }
}

extern "C" void kernel_launch(void* const* d_in, const int* in_sizes, int n_in,
                              void* d_out, int out_size, void* d_ws, size_t ws_size,
                              hipStream_t stream) {
  const float* x_t       = (const float*)d_in[0];
  const float* flat_state= (const float*)d_in[1];
  const float* W_in_cell = (const float*)d_in[2];
  const float* norm_w    = (const float*)d_in[3];
  const float* W_in      = (const float*)d_in[4];
  const float* conv_w    = (const float*)d_in[5];
  const float* conv_b    = (const float*)d_in[6];
  const float* W_xproj   = (const float*)d_in[7];
  const float* W_dt      = (const float*)d_in[8];
  const float* b_dt      = (const float*)d_in[9];
  const float* A_log     = (const float*)d_in[10];
  const float* D_param   = (const float*)d_in[11];
  const float* W_out     = (const float*)d_in[12];

  float* y_t_out = (float*)d_out;                       // B x D_MODEL
  float* outFlat = (float*)d_out + (size_t)B * D_MODEL; // B x ROW_STATE

  float* ws = (float*)d_ws;
  float* x     = ws;                                    // B x D_MODEL (residual)
  float* xz    = x + (size_t)B * D_MODEL;               // B x 2ED
  float* xs    = xz + (size_t)B * 2 * ED;               // B x ED
  float* dbc   = xs + (size_t)B * ED;                   // B x 96
  float* delta = dbc + (size_t)B * 96;                  // B x ED
  float* yz    = delta + (size_t)B * ED;                // B x ED
  float* Aneg  = yz + (size_t)B * ED;                   // FLAT_H
  ushort_t* us = (ushort_t*)(Aneg + FLAT_H);
  ushort_t* xt_hi   = us;  us += (size_t)B * D_IN;
  ushort_t* xt_lo   = us;  us += (size_t)B * D_IN;
  ushort_t* wic_hi  = us;  us += (size_t)D_MODEL * D_IN;
  ushort_t* wic_lo  = us;  us += (size_t)D_MODEL * D_IN;
  ushort_t* win_hi  = us;  us += (size_t)2 * ED * D_MODEL;
  ushort_t* win_lo  = us;  us += (size_t)2 * ED * D_MODEL;
  ushort_t* wout_hi = us;  us += (size_t)D_MODEL * ED;
  ushort_t* wout_lo = us;  us += (size_t)D_MODEL * ED;
  ushort_t* xn_hi   = us;  us += (size_t)B * D_MODEL;
  ushort_t* xn_lo   = us;  us += (size_t)B * D_MODEL;
  ushort_t* yz_hi   = us;  us += (size_t)B * ED;
  ushort_t* yz_lo   = us;  us += (size_t)B * ED;

  dim3 blk(256);

  // zero dbc for split-K atomic accumulation
  (void)hipMemsetAsync(dbc, 0, (size_t)B * 96 * sizeof(float), stream);

  // 0) pre-split weights + x_t into bf16 hi/lo
  split_kernel<<<dim3((B * D_IN) / 1024), blk, 0, stream>>>(x_t, xt_hi, xt_lo);
  split_kernel<<<dim3((D_MODEL * D_IN) / 1024), blk, 0, stream>>>(W_in_cell, wic_hi, wic_lo);
  split_kernel<<<dim3((2 * ED * D_MODEL) / 1024), blk, 0, stream>>>(W_in, win_hi, win_lo);
  split_kernel<<<dim3((D_MODEL * ED) / 1024), blk, 0, stream>>>(W_out, wout_hi, wout_lo);

  // 1) x = x_t @ W_in_cell^T                        (bf16-split MFMA, gl_lds)
  gemm_bs<0><<<dim3(D_MODEL / 128, B / 128), blk, 0, stream>>>(
      xt_hi, xt_lo, wic_hi, wic_lo, x, B, D_MODEL, D_IN, D_MODEL, nullptr);
  // 2) xn = rmsnorm(x) * norm_w  -> hi/lo bf16
  rmsnorm_split_kernel<<<dim3(B), blk, 0, stream>>>(x, norm_w, xn_hi, xn_lo);
  // 3) xz = xn @ W_in^T
  gemm_bs<0><<<dim3(2 * ED / 128, B / 128), blk, 0, stream>>>(
      xn_hi, xn_lo, win_hi, win_lo, xz, B, 2 * ED, D_MODEL, 2 * ED, nullptr);
  // 3b) Aneg = -exp(A_log)
  prep_aneg<<<dim3(FLAT_H / 1024), blk, 0, stream>>>(A_log, Aneg);
  // 4) conv + silu -> xs ; inputs_new -> flat_new
  conv_silu_kernel<<<dim3(B), blk, 0, stream>>>(
      flat_state, xz, conv_w, conv_b, xs, outFlat);
  // 5) dbc = xs @ W_xproj^T                         (scalar, split-K x8, atomic)
  gemm_nt_splitk<<<dim3(2, B / 64, 8), blk, 0, stream>>>(
      xs, W_xproj, dbc, B, 96, ED, ED, ED, 96);
  // 6) delta = softplus(dbc[:, :64] @ W_dt^T + b_dt)  (legacy MFMA, K=64)
  gemm_nt_mfma<1><<<dim3(ED / 128, B / 128), blk, 0, stream>>>(
      dbc, W_dt, delta, B, ED, DTDIM, 96, DTDIM, ED, b_dt);
  // 7) state update -> h_new (flat_new), yz
  state_kernel<<<dim3((size_t)B * FLAT_H / 1024), blk, 0, stream>>>(
      flat_state, xz, xs, dbc, delta, Aneg, D_param, outFlat, yz);
  // 7b) split yz
  split_kernel<<<dim3((B * ED) / 1024), blk, 0, stream>>>(yz, yz_hi, yz_lo);
  // 8) y_t = yz @ W_out^T + residual
  gemm_bs<2><<<dim3(D_MODEL / 128, B / 128), blk, 0, stream>>>(
      yz_hi, yz_lo, wout_hi, wout_lo, y_t_out, B, D_MODEL, ED, D_MODEL, x);
}